// Round 8
// baseline (26.950 us; speedup 1.0000x reference)
//
#include <hip/hip_runtime.h>
#include <math.h>

#define NQ 10
#define QDEPTH 4
#define BLK 256
#define WPS 4            // waves (samples) per block

typedef float v2f __attribute__((ext_vector_type(2)));

__device__ __forceinline__ int   asi(float v) { return __builtin_bit_cast(int, v); }
__device__ __forceinline__ float asf(int v)   { return __builtin_bit_cast(float, v); }

// guaranteed packed fp32 (VOP3P) — compiler often fails to form these from vector IR
__device__ __forceinline__ v2f pk_mul(v2f a, v2f b) {
    v2f d; asm("v_pk_mul_f32 %0, %1, %2" : "=v"(d) : "v"(a), "v"(b)); return d;
}
__device__ __forceinline__ v2f pk_fma(v2f a, v2f b, v2f c) {
    v2f d; asm("v_pk_fma_f32 %0, %1, %2, %3" : "=v"(d) : "v"(a), "v"(b), "v"(c)); return d;
}

// exact lane^D partner exchange; D=1,2 DPP (VALU), D=4,8,16 ds_swizzle, D=32 ds_bpermute
template<int D>
__device__ __forceinline__ float exch(float v, int addr32) {
    if constexpr (D == 1)
        return asf(__builtin_amdgcn_update_dpp(asi(v), asi(v), 0xB1, 0xF, 0xF, true));
    else if constexpr (D == 2)
        return asf(__builtin_amdgcn_update_dpp(asi(v), asi(v), 0x4E, 0xF, 0xF, true));
    else if constexpr (D == 4)
        return asf(__builtin_amdgcn_ds_swizzle(asi(v), 0x101F));
    else if constexpr (D == 8)
        return asf(__builtin_amdgcn_ds_swizzle(asi(v), 0x201F));
    else if constexpr (D == 16)
        return asf(__builtin_amdgcn_ds_swizzle(asi(v), 0x401F));
    else
        return asf(__builtin_amdgcn_ds_bpermute(addr32, asi(v)));
}

__device__ __forceinline__ float rlane(float v, int l) {
    return asf(__builtin_amdgcn_readlane(asi(v), l));
}

// local qubit Q (0..3): register butterflies, 2 pk ops per amplitude
template<int Q>
__device__ __forceinline__ void local_gate(v2f (&P)[16], float ct, float st) {
    v2f ct2 = {ct, ct}, st2 = {st, st}, nst2 = {-st, -st};
    #pragma unroll
    for (int pp = 0; pp < 8; ++pp) {
        const int i0 = ((pp >> Q) << (Q + 1)) | (pp & ((1 << Q) - 1));
        const int i1 = i0 | (1 << Q);
        v2f a = P[i0], b = P[i1];
        P[i0] = pk_fma(nst2, b, pk_mul(ct2, a));
        P[i1] = pk_fma(st2,  a, pk_mul(ct2, b));
    }
}

// cross qubit at lane distance D: P' = ct*P + stv*partner (stv carries per-lane sign)
template<int D>
__device__ __forceinline__ void cross_gate(v2f (&P)[16], float ct, float stv, int addr32) {
    v2f ct2 = {ct, ct}, sv2 = {stv, stv};
    #pragma unroll
    for (int r = 0; r < 16; ++r) {
        v2f pp;
        pp.x = exch<D>(P[r].x, addr32);
        pp.y = exch<D>(P[r].y, addr32);
        P[r] = pk_fma(sv2, pp, pk_mul(ct2, P[r]));
    }
}

__global__ __launch_bounds__(BLK, 4) void hybrid_kernel(
    const float* __restrict__ x,      // (B,10)
    const float* __restrict__ Ws,     // (5,10,10)
    const float* __restrict__ bs,     // (5,10)
    const float* __restrict__ theta,  // (4,10)
    const float* __restrict__ Wf,     // (2,20)
    const float* __restrict__ bfin,   // (2,)
    float* __restrict__ out)          // (B,2)
{
    const int tid  = threadIdx.x;
    const int lane = tid & 63;
    const int wv   = tid >> 6;
    const int s    = blockIdx.x * WPS + wv;   // sample index

    // ---- trig via lanes: 0..39 theta gates, 40..49 this sample's x
    float ang = 0.0f;
    if (lane < QDEPTH * NQ)              ang = theta[lane];
    else if (lane < QDEPTH * NQ + NQ)    ang = x[s * NQ + (lane - QDEPTH * NQ)];
    float sv_, cv_;
    sincosf(0.5f * ang, &sv_, &cv_);

    float cq[NQ], sq[NQ];
    #pragma unroll
    for (int q = 0; q < NQ; ++q) {
        cq[q] = rlane(cv_, QDEPTH * NQ + q);
        sq[q] = rlane(sv_, QDEPTH * NQ + q);
    }
    float lf = 1.0f;
    #pragma unroll
    for (int b = 0; b < 6; ++b)
        lf *= ((lane >> b) & 1) ? sq[4 + b] : cq[4 + b];

    // ---- init, original coords: amp_k = (-i)^popc(k) * r_k ; P[loc] = (re, im)
    const int pl = __popc(lane);
    v2f P[16];
    {
        float p01[4], p23[4];
        p01[0] = cq[0] * cq[1]; p01[1] = sq[0] * cq[1];
        p01[2] = cq[0] * sq[1]; p01[3] = sq[0] * sq[1];
        p23[0] = cq[2] * cq[3]; p23[1] = sq[2] * cq[3];
        p23[2] = cq[2] * sq[3]; p23[3] = sq[2] * sq[3];
        #pragma unroll
        for (int loc = 0; loc < 16; ++loc) {
            float r = lf * p01[loc & 3] * p23[loc >> 2];
            int pm = (pl + __popc(loc)) & 3;   // (-i)^pm
            P[loc].x = (pm == 0) ? r : ((pm == 2) ? -r : 0.0f);
            P[loc].y = (pm == 1) ? -r : ((pm == 3) ? r : 0.0f);
        }
    }

    // ---- per-lane masks
    int zmask[6];
    #pragma unroll
    for (int b = 0; b < 6; ++b)
        zmask[b] = ((lane >> b) & 1) << 31;     // sign-flip word when lane bit set
    const int addr32 = (lane ^ 32) << 2;        // ds_bpermute byte address

    // CZ sign words: par(k) = P1(loc) ^ (locbit3 & lanebit0) ^ P3(lane)
    const int p3  = __popc(lane & (lane >> 1)) & 1;
    const int sAw = p3 << 31;
    const int sBw = (p3 ^ (lane & 1)) << 31;
    const int sAn = sAw ^ 0x80000000;
    const int sBn = sBw ^ 0x80000000;

    // ---- circuit: 4 x (10 RY + CZ chain), real coords, zero barriers
    for (int l = 0; l < QDEPTH; ++l) {
        local_gate<0>(P, rlane(cv_, l * NQ + 0), rlane(sv_, l * NQ + 0));
        local_gate<1>(P, rlane(cv_, l * NQ + 1), rlane(sv_, l * NQ + 1));
        local_gate<2>(P, rlane(cv_, l * NQ + 2), rlane(sv_, l * NQ + 2));
        local_gate<3>(P, rlane(cv_, l * NQ + 3), rlane(sv_, l * NQ + 3));
        {
            float ct, stv;
            ct  = rlane(cv_, l * NQ + 4);
            stv = asf(asi(-rlane(sv_, l * NQ + 4)) ^ zmask[0]);
            cross_gate<1>(P, ct, stv, addr32);
            ct  = rlane(cv_, l * NQ + 5);
            stv = asf(asi(-rlane(sv_, l * NQ + 5)) ^ zmask[1]);
            cross_gate<2>(P, ct, stv, addr32);
            ct  = rlane(cv_, l * NQ + 6);
            stv = asf(asi(-rlane(sv_, l * NQ + 6)) ^ zmask[2]);
            cross_gate<4>(P, ct, stv, addr32);
            ct  = rlane(cv_, l * NQ + 7);
            stv = asf(asi(-rlane(sv_, l * NQ + 7)) ^ zmask[3]);
            cross_gate<8>(P, ct, stv, addr32);
            ct  = rlane(cv_, l * NQ + 8);
            stv = asf(asi(-rlane(sv_, l * NQ + 8)) ^ zmask[4]);
            cross_gate<16>(P, ct, stv, addr32);
            ct  = rlane(cv_, l * NQ + 9);
            stv = asf(asi(-rlane(sv_, l * NQ + 9)) ^ zmask[5]);
            cross_gate<32>(P, ct, stv, addr32);
        }
        // CZ chain: sign-bit XOR
        #pragma unroll
        for (int loc = 0; loc < 16; ++loc) {
            const int C1 = __popc(loc & (loc >> 1)) & 1;
            const int m  = (loc & 8) ? (C1 ? sBn : sBw) : (C1 ? sAn : sAw);
            P[loc].x = asf(asi(P[loc].x) ^ m);
            P[loc].y = asf(asi(P[loc].y) ^ m);
        }
    }

    // ---- probs + folded quantum->output contraction
    // zq[b] (b<4) = S - 2*U_b, U_b = sum of pr over locs with bit b set
    // coef of zq[q] in out_t is Wf[t*20 + 19 - q]
    float pr[16], S = 0.0f;
    #pragma unroll
    for (int loc = 0; loc < 16; ++loc) {
        v2f Q = pk_mul(P[loc], P[loc]);
        pr[loc] = Q.x + Q.y;
        S += pr[loc];
    }
    float U0 = 0.0f, U1 = 0.0f, U2 = 0.0f, U3 = 0.0f;
    #pragma unroll
    for (int loc = 0; loc < 16; ++loc) {
        if (loc & 1) U0 += pr[loc];
        if (loc & 2) U1 += pr[loc];
        if (loc & 4) U2 += pr[loc];
        if (loc & 8) U3 += pr[loc];
    }
    const float w00 = Wf[19], w01 = Wf[18], w02 = Wf[17], w03 = Wf[16];
    const float w10 = Wf[39], w11 = Wf[38], w12 = Wf[37], w13 = Wf[36];
    float d0 = ((w00 + w01) + (w02 + w03)) * S;
    float d1 = ((w10 + w11) + (w12 + w13)) * S;
    d0 = fmaf(-2.0f * w00, U0, d0); d0 = fmaf(-2.0f * w01, U1, d0);
    d0 = fmaf(-2.0f * w02, U2, d0); d0 = fmaf(-2.0f * w03, U3, d0);
    d1 = fmaf(-2.0f * w10, U0, d1); d1 = fmaf(-2.0f * w11, U1, d1);
    d1 = fmaf(-2.0f * w12, U2, d1); d1 = fmaf(-2.0f * w13, U3, d1);
    float L0 = 0.0f, L1 = 0.0f;
    #pragma unroll
    for (int b = 0; b < 6; ++b) {      // q = 4+b -> Wf[15-b] / Wf[35-b]
        L0 += asf(asi(Wf[15 - b]) ^ zmask[b]);
        L1 += asf(asi(Wf[35 - b]) ^ zmask[b]);
    }
    float qp0 = fmaf(L0, S, d0);
    float qp1 = fmaf(L1, S, d1);
    // reduce the 2 partials across 64 lanes
    qp0 += exch<1>(qp0, addr32);  qp1 += exch<1>(qp1, addr32);
    qp0 += exch<2>(qp0, addr32);  qp1 += exch<2>(qp1, addr32);
    qp0 += exch<4>(qp0, addr32);  qp1 += exch<4>(qp1, addr32);
    qp0 += exch<8>(qp0, addr32);  qp1 += exch<8>(qp1, addr32);
    qp0 += exch<16>(qp0, addr32); qp1 += exch<16>(qp1, addr32);
    qp0 += exch<32>(qp0, addr32); qp1 += exch<32>(qp1, addr32);

    // ---- classical MLP: lane i (<10) owns row i; broadcasts via readlane
    const int row = (lane < NQ) ? lane : 0;
    float h = x[s * NQ + row];
    #pragma unroll
    for (int l = 0; l < QDEPTH; ++l) {
        float v = bs[l * NQ + row];
        #pragma unroll
        for (int j = 0; j < NQ; ++j)
            v = fmaf(Ws[(l * NQ + row) * NQ + j], rlane(h, j), v);
        h = fmaxf(v, 0.0f);
    }
    float cls = bs[QDEPTH * NQ + row];
    #pragma unroll
    for (int j = 0; j < NQ; ++j)
        cls = fmaf(Ws[(QDEPTH * NQ + row) * NQ + j], rlane(h, j), cls);

    // ---- final linear
    float o0 = bfin[0] + qp0, o1 = bfin[1] + qp1;
    #pragma unroll
    for (int j = 0; j < NQ; ++j) {
        float cj = rlane(cls, j);
        o0 = fmaf(Wf[j],      cj, o0);
        o1 = fmaf(Wf[20 + j], cj, o1);
    }
    if (lane == 0) {
        float2 o; o.x = o0; o.y = o1;
        *reinterpret_cast<float2*>(&out[s * 2]) = o;
    }
}

extern "C" void kernel_launch(void* const* d_in, const int* in_sizes, int n_in,
                              void* d_out, int out_size, void* d_ws, size_t ws_size,
                              hipStream_t stream) {
    const float* x     = (const float*)d_in[0];   // (4096,10)
    const float* Ws    = (const float*)d_in[1];   // (5,10,10)
    const float* bs    = (const float*)d_in[2];   // (5,10)
    const float* theta = (const float*)d_in[3];   // (4,10)
    const float* Wf    = (const float*)d_in[4];   // (2,20)
    const float* bfin  = (const float*)d_in[5];   // (2,)
    float* out = (float*)d_out;

    const int B = in_sizes[0] / NQ;               // 4096
    hybrid_kernel<<<B / WPS, BLK, 0, stream>>>(x, Ws, bs, theta, Wf, bfin, out);
}

// Round 9
// 24.790 us; speedup vs baseline: 1.0871x; 1.0871x over previous
//
#include <hip/hip_runtime.h>
#include <math.h>

#define NQ 10
#define QDEPTH 4
#define BLK 256
#define WPS 4            // waves (samples) per block

typedef float v2f __attribute__((ext_vector_type(2)));

__device__ __forceinline__ int   asi(float v) { return __builtin_bit_cast(int, v); }
__device__ __forceinline__ float asf(int v)   { return __builtin_bit_cast(float, v); }

// exact lane^D partner exchange; D=1,2 DPP (VALU), D=4,8,16 ds_swizzle, D=32 ds_bpermute
template<int D>
__device__ __forceinline__ float exch(float v, int addr32) {
    if constexpr (D == 1)
        return asf(__builtin_amdgcn_update_dpp(asi(v), asi(v), 0xB1, 0xF, 0xF, true));
    else if constexpr (D == 2)
        return asf(__builtin_amdgcn_update_dpp(asi(v), asi(v), 0x4E, 0xF, 0xF, true));
    else if constexpr (D == 4)
        return asf(__builtin_amdgcn_ds_swizzle(asi(v), 0x101F));
    else if constexpr (D == 8)
        return asf(__builtin_amdgcn_ds_swizzle(asi(v), 0x201F));
    else if constexpr (D == 16)
        return asf(__builtin_amdgcn_ds_swizzle(asi(v), 0x401F));
    else
        return asf(__builtin_amdgcn_ds_bpermute(addr32, asi(v)));
}

__device__ __forceinline__ float rlane(float v, int l) {
    return asf(__builtin_amdgcn_readlane(asi(v), l));
}

// local qubit Q (0..3), SHEAR form: (a,b) -> (a - t*b, b + t*a). 1 fma per reg.
template<int Q>
__device__ __forceinline__ void local_gate_t(v2f (&P)[16], float t) {
    const v2f tt = {t, t};
    #pragma unroll
    for (int pp = 0; pp < 8; ++pp) {
        const int i0 = ((pp >> Q) << (Q + 1)) | (pp & ((1 << Q) - 1));
        const int i1 = i0 | (1 << Q);
        v2f a = P[i0], b = P[i1];
        P[i0] = a - tt * b;
        P[i1] = b + tt * a;
    }
}

// cross qubit at lane distance D, SHEAR form: P' = P + tvv*partner (tvv has per-lane sign)
template<int D>
__device__ __forceinline__ void cross_gate_t(v2f (&P)[16], float tvv, int addr32) {
    const v2f tt = {tvv, tvv};
    #pragma unroll
    for (int r = 0; r < 16; ++r) {
        v2f pp;
        pp.x = exch<D>(P[r].x, addr32);
        pp.y = exch<D>(P[r].y, addr32);
        P[r] = P[r] + tt * pp;
    }
}

__global__ __launch_bounds__(BLK, 4) void hybrid_kernel(
    const float* __restrict__ x,      // (B,10)
    const float* __restrict__ Ws,     // (5,10,10)
    const float* __restrict__ bs,     // (5,10)
    const float* __restrict__ theta,  // (4,10)
    const float* __restrict__ Wf,     // (2,20)
    const float* __restrict__ bfin,   // (2,)
    float* __restrict__ out)          // (B,2)
{
    const int tid  = threadIdx.x;
    const int lane = tid & 63;
    const int wv   = tid >> 6;
    const int s    = blockIdx.x * WPS + wv;   // sample index

    // ---- trig via lanes: 0..39 theta gates, 40..49 this sample's x
    float ang = 0.0f;
    if (lane < QDEPTH * NQ)              ang = theta[lane];
    else if (lane < QDEPTH * NQ + NQ)    ang = x[s * NQ + (lane - QDEPTH * NQ)];
    float sv_, cv_;
    sincosf(0.5f * ang, &sv_, &cv_);
    const float tv_ = sv_ / cv_;              // tan(ang/2) (lanes 0..39 used)

    const int addr32 = (lane ^ 32) << 2;      // ds_bpermute byte address

    // wave-uniform C = prod over the 40 gates of cos(theta/2); C2 scales probs
    float cc = (lane < QDEPTH * NQ) ? cv_ : 1.0f;
    cc *= exch<1>(cc, addr32);
    cc *= exch<2>(cc, addr32);
    cc *= exch<4>(cc, addr32);
    cc *= exch<8>(cc, addr32);
    cc *= exch<16>(cc, addr32);
    cc *= exch<32>(cc, addr32);
    const float C2 = cc * cc;

    // ---- init, original coords: amp_k = (-i)^popc(k) * r_k ; P[loc] = (re, im)
    const int pl = __popc(lane);
    v2f P[16];
    {
        float cq[4], sq[4];
        #pragma unroll
        for (int q = 0; q < 4; ++q) {
            cq[q] = rlane(cv_, QDEPTH * NQ + q);
            sq[q] = rlane(sv_, QDEPTH * NQ + q);
        }
        float lf = 1.0f;
        #pragma unroll
        for (int b = 0; b < 6; ++b) {
            float cb = rlane(cv_, QDEPTH * NQ + 4 + b);
            float sb = rlane(sv_, QDEPTH * NQ + 4 + b);
            lf *= ((lane >> b) & 1) ? sb : cb;
        }
        float p01[4], p23[4];
        p01[0] = cq[0] * cq[1]; p01[1] = sq[0] * cq[1];
        p01[2] = cq[0] * sq[1]; p01[3] = sq[0] * sq[1];
        p23[0] = cq[2] * cq[3]; p23[1] = sq[2] * cq[3];
        p23[2] = cq[2] * sq[3]; p23[3] = sq[2] * sq[3];
        #pragma unroll
        for (int loc = 0; loc < 16; ++loc) {
            float r = lf * p01[loc & 3] * p23[loc >> 2];
            int pm = (pl + __popc(loc)) & 3;   // (-i)^pm
            P[loc].x = (pm == 0) ? r : ((pm == 2) ? -r : 0.0f);
            P[loc].y = (pm == 1) ? -r : ((pm == 3) ? r : 0.0f);
        }
    }

    // ---- per-lane masks
    int zmask[6];
    #pragma unroll
    for (int b = 0; b < 6; ++b)
        zmask[b] = ((lane >> b) & 1) << 31;     // sign-flip word when lane bit set

    // CZ sign words: par(k) = P1(loc) ^ (locbit3 & lanebit0) ^ P3(lane)
    const int p3  = __popc(lane & (lane >> 1)) & 1;
    const int sAw = p3 << 31;
    const int sBw = (p3 ^ (lane & 1)) << 31;
    const int sAn = sAw ^ 0x80000000;
    const int sBn = sBw ^ 0x80000000;

    // ---- circuit: 4 x (10 RY shears + CZ chain); global factor C applied at the end
    for (int l = 0; l < QDEPTH; ++l) {
        local_gate_t<0>(P, rlane(tv_, l * NQ + 0));
        local_gate_t<1>(P, rlane(tv_, l * NQ + 1));
        local_gate_t<2>(P, rlane(tv_, l * NQ + 2));
        local_gate_t<3>(P, rlane(tv_, l * NQ + 3));
        {
            float tvv;
            tvv = asf(asi(-rlane(tv_, l * NQ + 4)) ^ zmask[0]);
            cross_gate_t<1>(P, tvv, addr32);
            tvv = asf(asi(-rlane(tv_, l * NQ + 5)) ^ zmask[1]);
            cross_gate_t<2>(P, tvv, addr32);
            tvv = asf(asi(-rlane(tv_, l * NQ + 6)) ^ zmask[2]);
            cross_gate_t<4>(P, tvv, addr32);
            tvv = asf(asi(-rlane(tv_, l * NQ + 7)) ^ zmask[3]);
            cross_gate_t<8>(P, tvv, addr32);
            tvv = asf(asi(-rlane(tv_, l * NQ + 8)) ^ zmask[4]);
            cross_gate_t<16>(P, tvv, addr32);
            tvv = asf(asi(-rlane(tv_, l * NQ + 9)) ^ zmask[5]);
            cross_gate_t<32>(P, tvv, addr32);
        }
        // CZ chain: sign-bit XOR
        #pragma unroll
        for (int loc = 0; loc < 16; ++loc) {
            const int C1 = __popc(loc & (loc >> 1)) & 1;
            const int m  = (loc & 8) ? (C1 ? sBn : sBw) : (C1 ? sAn : sAw);
            P[loc].x = asf(asi(P[loc].x) ^ m);
            P[loc].y = asf(asi(P[loc].y) ^ m);
        }
    }

    // ---- probs (unscaled) + folded quantum->output contraction
    // true pr = C2 * (x^2 + y^2); apply C2 once at the end (contraction is linear in pr)
    float pr[16], S = 0.0f;
    #pragma unroll
    for (int loc = 0; loc < 16; ++loc) {
        pr[loc] = fmaf(P[loc].x, P[loc].x, P[loc].y * P[loc].y);
        S += pr[loc];
    }
    float U0 = 0.0f, U1 = 0.0f, U2 = 0.0f, U3 = 0.0f;
    #pragma unroll
    for (int loc = 0; loc < 16; ++loc) {
        if (loc & 1) U0 += pr[loc];
        if (loc & 2) U1 += pr[loc];
        if (loc & 4) U2 += pr[loc];
        if (loc & 8) U3 += pr[loc];
    }
    const float w00 = Wf[19], w01 = Wf[18], w02 = Wf[17], w03 = Wf[16];
    const float w10 = Wf[39], w11 = Wf[38], w12 = Wf[37], w13 = Wf[36];
    float d0 = ((w00 + w01) + (w02 + w03)) * S;
    float d1 = ((w10 + w11) + (w12 + w13)) * S;
    d0 = fmaf(-2.0f * w00, U0, d0); d0 = fmaf(-2.0f * w01, U1, d0);
    d0 = fmaf(-2.0f * w02, U2, d0); d0 = fmaf(-2.0f * w03, U3, d0);
    d1 = fmaf(-2.0f * w10, U0, d1); d1 = fmaf(-2.0f * w11, U1, d1);
    d1 = fmaf(-2.0f * w12, U2, d1); d1 = fmaf(-2.0f * w13, U3, d1);
    float L0 = 0.0f, L1 = 0.0f;
    #pragma unroll
    for (int b = 0; b < 6; ++b) {      // q = 4+b -> Wf[15-b] / Wf[35-b]
        L0 += asf(asi(Wf[15 - b]) ^ zmask[b]);
        L1 += asf(asi(Wf[35 - b]) ^ zmask[b]);
    }
    float qp0 = fmaf(L0, S, d0);
    float qp1 = fmaf(L1, S, d1);
    // reduce the 2 partials across 64 lanes
    qp0 += exch<1>(qp0, addr32);  qp1 += exch<1>(qp1, addr32);
    qp0 += exch<2>(qp0, addr32);  qp1 += exch<2>(qp1, addr32);
    qp0 += exch<4>(qp0, addr32);  qp1 += exch<4>(qp1, addr32);
    qp0 += exch<8>(qp0, addr32);  qp1 += exch<8>(qp1, addr32);
    qp0 += exch<16>(qp0, addr32); qp1 += exch<16>(qp1, addr32);
    qp0 += exch<32>(qp0, addr32); qp1 += exch<32>(qp1, addr32);

    // ---- classical MLP: lane i (<10) owns row i; broadcasts via readlane
    const int row = (lane < NQ) ? lane : 0;
    float h = x[s * NQ + row];
    #pragma unroll
    for (int l = 0; l < QDEPTH; ++l) {
        float v = bs[l * NQ + row];
        #pragma unroll
        for (int j = 0; j < NQ; ++j)
            v = fmaf(Ws[(l * NQ + row) * NQ + j], rlane(h, j), v);
        h = fmaxf(v, 0.0f);
    }
    float cls = bs[QDEPTH * NQ + row];
    #pragma unroll
    for (int j = 0; j < NQ; ++j)
        cls = fmaf(Ws[(QDEPTH * NQ + row) * NQ + j], rlane(h, j), cls);

    // ---- final linear (C2 scales the quantum contribution)
    float o0 = fmaf(C2, qp0, bfin[0]);
    float o1 = fmaf(C2, qp1, bfin[1]);
    #pragma unroll
    for (int j = 0; j < NQ; ++j) {
        float cj = rlane(cls, j);
        o0 = fmaf(Wf[j],      cj, o0);
        o1 = fmaf(Wf[20 + j], cj, o1);
    }
    if (lane == 0) {
        float2 o; o.x = o0; o.y = o1;
        *reinterpret_cast<float2*>(&out[s * 2]) = o;
    }
}

extern "C" void kernel_launch(void* const* d_in, const int* in_sizes, int n_in,
                              void* d_out, int out_size, void* d_ws, size_t ws_size,
                              hipStream_t stream) {
    const float* x     = (const float*)d_in[0];   // (4096,10)
    const float* Ws    = (const float*)d_in[1];   // (5,10,10)
    const float* bs    = (const float*)d_in[2];   // (5,10)
    const float* theta = (const float*)d_in[3];   // (4,10)
    const float* Wf    = (const float*)d_in[4];   // (2,20)
    const float* bfin  = (const float*)d_in[5];   // (2,)
    float* out = (float*)d_out;

    const int B = in_sizes[0] / NQ;               // 4096
    hybrid_kernel<<<B / WPS, BLK, 0, stream>>>(x, Ws, bs, theta, Wf, bfin, out);
}